// Round 10
// baseline (913.621 us; speedup 1.0000x reference)
//
#include <hip/hip_runtime.h>
#include <math.h>

// GridLSTM two-phase (L/U) dataflow cell, fused f16 weights. V=50000,E=300,H=128,L=32,B=8.
// 256 blocks x 256 threads. bid = c*32 + i (i = grid row, c = t-slice chunk 0..7).
// gates = WU@ho_up + WL@ho_left + (Pproj+b) + Hypproj + upok*bU + lfok*bL,
// WU = W_hh[:,:128]@W_ch (1024x256), WL = W_hh[:,128:]@W_ch (1024x256), f16-packed.
// Each thread holds BOTH an up-K-seg and a left-K-seg (w_u[4][16]+w_l[4][16] h2),
// so phase L (left dep, same row, early) runs the WL half off the critical path,
// and phase U (up dep, previous row, late) runs only WU + finish. Critical path
// per down-edge = up-detect + stage-up + half-GEMM + reduce + publish.
// c_in slice: W_cc rows [(c&3)*32..+32) fp32 (up side for c<4, left for c>=4).
// Sync protocol (proven r5-r9): relaxed agent-scope atomics for data; producer:
// data stores -> s_waitcnt vmcnt(0) -> __syncthreads -> relaxed flag store.
// Flags monotonic from ws poison base 0xAAAAAAAA.

typedef _Float16 h2 __attribute__((ext_vector_type(2)));

__device__ __forceinline__ h2 pk_f16(float a, float b) {
    return __builtin_bit_cast(h2, __builtin_amdgcn_cvt_pkrtz(a, b));
}

// ---------------- workspace layout (float words) ----------------
#define HYP_OFF   0            // Hypproj [32 j][8 b][1024]          (atomic)
#define HO_OFF    262144       // Ho raw [4 dep][32 j][8 b][256]     (atomic)
#define CO_OFF    524288       // Co raw [4 dep][32 j][8 b][256]     (atomic)
#define WP_OFF    786432       // fused wts packed h2 [1024 g][256]  (atomic, uint)
#define B_OFF     1048576      // bU[1024] | bL[1024]
#define FLAGS_OFF 1050624      // HF [(i*8+c)*16] (4096) | InitF [p*16] (4096)

#define BASE 0xAAAAAAAAu

__device__ __forceinline__ float sigm(float x) { return 1.f / (1.f + __expf(-x)); }
__device__ __forceinline__ float tanh_fast(float x) { return 1.f - 2.f / (__expf(2.f * x) + 1.f); }

__device__ __forceinline__ unsigned ld_flag(const unsigned* p) {
    return __hip_atomic_load(p, __ATOMIC_RELAXED, __HIP_MEMORY_SCOPE_AGENT);
}
__device__ __forceinline__ void st_flag(unsigned* p, unsigned v) {
    __hip_atomic_store(p, v, __ATOMIC_RELAXED, __HIP_MEMORY_SCOPE_AGENT);
}
__device__ __forceinline__ float ld_f32(const float* p) {
    unsigned u = __hip_atomic_load((const unsigned*)p, __ATOMIC_RELAXED, __HIP_MEMORY_SCOPE_AGENT);
    return __uint_as_float(u);
}
__device__ __forceinline__ void st_f32(float* p, float v) {
    __hip_atomic_store((unsigned*)p, __float_as_uint(v), __ATOMIC_RELAXED, __HIP_MEMORY_SCOPE_AGENT);
}
__device__ __forceinline__ void st_u32(unsigned* p, unsigned v) {
    __hip_atomic_store(p, v, __ATOMIC_RELAXED, __HIP_MEMORY_SCOPE_AGENT);
}
__device__ __forceinline__ float2 ld_f32x2(const float* p) {   // 8B-aligned
    unsigned long long u = __hip_atomic_load((const unsigned long long*)p,
                                             __ATOMIC_RELAXED, __HIP_MEMORY_SCOPE_AGENT);
    float2 r; r.x = __uint_as_float((unsigned)u); r.y = __uint_as_float((unsigned)(u >> 32));
    return r;
}
__device__ __forceinline__ void ld_u32x2(const unsigned* p, unsigned& a, unsigned& b) {
    unsigned long long u = __hip_atomic_load((const unsigned long long*)p,
                                             __ATOMIC_RELAXED, __HIP_MEMORY_SCOPE_AGENT);
    a = (unsigned)u; b = (unsigned)(u >> 32);
}
__device__ __forceinline__ void wait_ge(const unsigned* f, unsigned target) {
    long spins = 0;
    while ((ld_flag(f) - BASE) < target) {
        __builtin_amdgcn_s_sleep(1);
        if (++spins > (1L << 22)) break;   // failsafe: wrong answer > hang
    }
}
__device__ __forceinline__ void drain_vmem() {
    asm volatile("s_waitcnt vmcnt(0)" ::: "memory");
}

__global__ void __launch_bounds__(256, 1) grid_lstm_kernel(
    const int* __restrict__ premise, const int* __restrict__ hypothesis,
    const float* __restrict__ emb,
    const float* __restrict__ W_ih, const float* __restrict__ b_ih,
    const float* __restrict__ W_hh, const float* __restrict__ b_hh,
    const float* __restrict__ W_ch, const float* __restrict__ b_ch,
    const float* __restrict__ W_cc, const float* __restrict__ b_cc,
    const float* __restrict__ W1, const float* __restrict__ b1,
    const float* __restrict__ W2, const float* __restrict__ b2,
    const float* __restrict__ W3, const float* __restrict__ b3,
    float* __restrict__ out, float* __restrict__ ws)
{
    __shared__ h2    hAB[2048];      // f16 [8 b][256]: kk<128 up-half, kk>=128 left-half
    __shared__ float sCo[2048];      // f32 co_side [8 b][256]
    __shared__ float ppL[1024];      // Pproj slice [8 b][128 g], g=(a<<5)|s
    __shared__ float red[8448];      // gate partials [256][33] / embs / MLP
    __shared__ float red2[2304];     // c partials [256][9]

    const int tid = threadIdx.x;
    const int bid = blockIdx.x;
    const int i   = bid & 31;       // grid row
    const int c   = bid >> 5;       // t-slice chunk

    float*    Hypproj = ws + HYP_OFF;
    float*    Ho      = ws + HO_OFF;
    float*    Co      = ws + CO_OFF;
    unsigned* WP      = (unsigned*)(ws + WP_OFF);
    float*    BU      = ws + B_OFF;
    float*    BL      = ws + B_OFF + 1024;
    unsigned* HF      = (unsigned*)(ws + FLAGS_OFF);          // [(i*8+c)*16]
    unsigned* InitF   = (unsigned*)(ws + FLAGS_OFF) + 4096;   // [p*16]

    const int tq = tid & 31, ks = tid >> 5;   // GEMM K-split coords
    const int tl = tid & 31, bb = tid >> 5;   // elementwise coords (t_local, batch)

    // ================= Init A: Pproj (LDS) + Hypproj for this block's gate rows ====
    {
        float* embs = red;   // [2 sides][8][300] = 4800 floats
        for (int idx = tid; idx < 4800; idx += 256) {
            int side = idx / 2400, rem = idx - side * 2400;
            int b = rem / 300, e = rem - b * 300;
            const int* toks = side ? hypothesis : premise;
            embs[idx] = emb[(long)toks[b * 32 + i] * 300 + e];
        }
        __syncthreads();
        #pragma unroll 1
        for (int q = 0; q < 4; q++) {
            const int oo = tid + q * 256;
            const int b = oo >> 7, g = oo & 127;
            const int gr = (g >> 5) * 256 + c * 32 + (g & 31);   // t-sliced gate row
            float accP = b_ih[gr] + b_hh[gr];
            float accH = 0.f;
            const float* wp = W_ih + (long)gr * 600;
            const float* eP = embs + b * 300;
            const float* eH = embs + 2400 + b * 300;
            for (int e = 0; e < 300; e += 4) {
                float4 w1 = *(const float4*)(wp + e);
                float4 w2v = *(const float4*)(wp + 300 + e);
                float4 p4 = *(const float4*)(eP + e);
                float4 h4 = *(const float4*)(eH + e);
                accP += w1.x * p4.x + w1.y * p4.y + w1.z * p4.z + w1.w * p4.w;
                accH += w2v.x * h4.x + w2v.y * h4.y + w2v.z * h4.z + w2v.w * h4.w;
            }
            st_f32(&Hypproj[i * 8192 + b * 1024 + gr], accH);     // cross-block
            ppL[b * 128 + g] = accP;                              // block-local
        }
        __syncthreads();   // embs (red) free
    }

    // ================= Init B: fused weight rows [4*bid, 4*bid+4) =================
    {
        const int tr = tid >> 6, col = (tid & 63) * 4;
        const int r  = bid * 4 + tr;
        float u[4] = {0.f, 0.f, 0.f, 0.f}, l[4] = {0.f, 0.f, 0.f, 0.f};
        const float* whU = W_hh + (long)r * 256;
        const float* whL = whU + 128;
        for (int k = 0; k < 128; k++) {
            const float wu = whU[k], wl = whL[k];
            float4 wc = *(const float4*)(W_ch + (long)k * 256 + col);
            u[0] += wu * wc.x; u[1] += wu * wc.y; u[2] += wu * wc.z; u[3] += wu * wc.w;
            l[0] += wl * wc.x; l[1] += wl * wc.y; l[2] += wl * wc.z; l[3] += wl * wc.w;
        }
        unsigned* wrow = WP + (long)r * 256;
        st_u32(&wrow[col / 2],       __builtin_bit_cast(unsigned, __builtin_amdgcn_cvt_pkrtz(u[0], u[1])));
        st_u32(&wrow[col / 2 + 1],   __builtin_bit_cast(unsigned, __builtin_amdgcn_cvt_pkrtz(u[2], u[3])));
        st_u32(&wrow[128 + col / 2],     __builtin_bit_cast(unsigned, __builtin_amdgcn_cvt_pkrtz(l[0], l[1])));
        st_u32(&wrow[128 + col / 2 + 1], __builtin_bit_cast(unsigned, __builtin_amdgcn_cvt_pkrtz(l[2], l[3])));
        if ((tid & 63) == 0) {   // bias projections for this row
            float su = 0.f, sl = 0.f;
            for (int k = 0; k < 128; k++) { su += whU[k] * b_ch[k]; sl += whL[k] * b_ch[k]; }
            st_f32(&BU[r], su); st_f32(&BL[r], sl);
        }
    }
    drain_vmem();
    __syncthreads();
    if (tid == 0) st_flag(&InitF[bid * 16], BASE + 1u);

    // ---- wait ALL inits (covers every Hypproj row + all fused weights) ----
    wait_ge(&InitF[tid * 16], 1u);
    __syncthreads();

    // ---- fused weight slices -> registers: up K-seg + left K-seg per thread ----
    h2 w_u[4][16], w_l[4][16];    // 64 + 64 VGPRs
    #pragma unroll
    for (int a = 0; a < 4; a++) {
        const unsigned* srcU = WP + (long)(a * 256 + c * 32 + tq) * 256 + ks * 16;
        const unsigned* srcL = srcU + 128;
        #pragma unroll
        for (int m = 0; m < 8; m++) {
            unsigned lo, hi;
            ld_u32x2(srcU + m * 2, lo, hi);
            w_u[a][2 * m]     = __builtin_bit_cast(h2, lo);
            w_u[a][2 * m + 1] = __builtin_bit_cast(h2, hi);
            ld_u32x2(srcL + m * 2, lo, hi);
            w_l[a][2 * m]     = __builtin_bit_cast(h2, lo);
            w_l[a][2 * m + 1] = __builtin_bit_cast(h2, hi);
        }
    }
    float4 w3[8];                 // 32 VGPRs: W_cc row (c&3)*32+tq, K-seg ks*32..+32
    {
        const float* wr = W_cc + (long)((c & 3) * 32 + tq) * 256 + ks * 32;
        #pragma unroll
        for (int m = 0; m < 8; m++) w3[m] = *(const float4*)(wr + m * 4);
    }
    float bUv[4], bLv[4];
    #pragma unroll
    for (int a = 0; a < 4; a++) {
        bUv[a] = ld_f32(&BU[a * 256 + c * 32 + tl]);
        bLv[a] = ld_f32(&BL[a * 256 + c * 32 + tl]);
    }

    // ================= Wavefront: row i walks j = 0..31 =================
    #pragma unroll 1
    for (int j = 0; j < 32; j++) {
        const bool upok = (i > 0), lfok = (j > 0);
        const bool cok  = (c < 4) ? upok : lfok;
        const int  jl   = lfok ? (j - 1) : 0;

        // ============ Phase L: left dependency (same row — available early) ========
        if (lfok && tid < 8) wait_ge(&HF[(i * 8 + tid) * 16], (unsigned)j);
        __syncthreads();

        // prefetch Hypproj for elementwise (no cell dependency)
        float hyv[4];
        #pragma unroll
        for (int a = 0; a < 4; a++)
            hyv[a] = ld_f32(&Hypproj[j * 8192 + bb * 1024 + a * 256 + c * 32 + tl]);

        // stage ho_left (f16) and, for c>=4, co_left (f32)
        const float* HoLf = Ho + (((i & 3) * 32 + jl) * 2048);
        const float* CoLf = Co + (((i & 3) * 32 + jl) * 2048);
        #pragma unroll
        for (int r = 0; r < 4; r++) {
            const int idx = r * 256 + tid;           // 0..1023
            const int b = idx >> 7, kk = idx & 127;
            float2 l = lfok ? ld_f32x2(HoLf + b * 256 + 2 * kk) : make_float2(0.f, 0.f);
            hAB[b * 256 + 128 + kk] = pk_f16(l.x, l.y);
            if (c >= 4) {
                float2 cv = lfok ? ld_f32x2(CoLf + b * 256 + 2 * kk) : make_float2(0.f, 0.f);
                sCo[b * 256 + 2 * kk] = cv.x; sCo[b * 256 + 2 * kk + 1] = cv.y;
            }
        }
        __syncthreads();

        // GEMM left half (all threads) + c-path for c>=4
        float acc[4][8], a3[8];
        #pragma unroll
        for (int a = 0; a < 4; a++)
            #pragma unroll
            for (int b = 0; b < 8; b++) acc[a][b] = 0.f;
        #pragma unroll
        for (int b = 0; b < 8; b++) a3[b] = 0.f;
        #pragma unroll
        for (int b = 0; b < 8; b++) {
            const h2* hb = hAB + b * 256 + 128 + ks * 16;
            #pragma unroll
            for (int m4 = 0; m4 < 4; m4++) {
                uint4 hu = *(const uint4*)(hb + m4 * 4);
                h2 h0 = __builtin_bit_cast(h2, hu.x);
                h2 h1 = __builtin_bit_cast(h2, hu.y);
                h2 h2v = __builtin_bit_cast(h2, hu.z);
                h2 h3 = __builtin_bit_cast(h2, hu.w);
                #pragma unroll
                for (int a = 0; a < 4; a++) {
                    acc[a][b] = __builtin_amdgcn_fdot2(w_l[a][m4 * 4],     h0,  acc[a][b], false);
                    acc[a][b] = __builtin_amdgcn_fdot2(w_l[a][m4 * 4 + 1], h1,  acc[a][b], false);
                    acc[a][b] = __builtin_amdgcn_fdot2(w_l[a][m4 * 4 + 2], h2v, acc[a][b], false);
                    acc[a][b] = __builtin_amdgcn_fdot2(w_l[a][m4 * 4 + 3], h3,  acc[a][b], false);
                }
            }
            if (c >= 4) {
                const float* cb = sCo + b * 256 + ks * 32;
                #pragma unroll
                for (int m = 0; m < 8; m++) {
                    float4 cv = *(const float4*)(cb + m * 4);
                    a3[b] += w3[m].x * cv.x + w3[m].y * cv.y + w3[m].z * cv.z + w3[m].w * cv.w;
                }
            }
        }

        // ============ Phase U: up dependency (previous row — the critical edge) ====
        if (upok && tid < 8) wait_ge(&HF[((i - 1) * 8 + tid) * 16], (unsigned)(j + 1));
        __syncthreads();

        const float* HoUp = Ho + ((((i - 1) & 3) * 32 + j) * 2048);
        const float* CoUp = Co + ((((i - 1) & 3) * 32 + j) * 2048);
        #pragma unroll
        for (int r = 0; r < 4; r++) {
            const int idx = r * 256 + tid;
            const int b = idx >> 7, kk = idx & 127;
            float2 u = upok ? ld_f32x2(HoUp + b * 256 + 2 * kk) : make_float2(0.f, 0.f);
            hAB[b * 256 + kk] = pk_f16(u.x, u.y);
            if (c < 4) {
                float2 cv = upok ? ld_f32x2(CoUp + b * 256 + 2 * kk) : make_float2(0.f, 0.f);
                sCo[b * 256 + 2 * kk] = cv.x; sCo[b * 256 + 2 * kk + 1] = cv.y;
            }
        }
        __syncthreads();

        // GEMM up half + c-path for c<4
        #pragma unroll
        for (int b = 0; b < 8; b++) {
            const h2* hb = hAB + b * 256 + ks * 16;
            #pragma unroll
            for (int m4 = 0; m4 < 4; m4++) {
                uint4 hu = *(const uint4*)(hb + m4 * 4);
                h2 h0 = __builtin_bit_cast(h2, hu.x);
                h2 h1 = __builtin_bit_cast(h2, hu.y);
                h2 h2v = __builtin_bit_cast(h2, hu.z);
                h2 h3 = __builtin_bit_cast(h2, hu.w);
                #pragma unroll
                for (int a = 0; a < 4; a++) {
                    acc[a][b] = __builtin_amdgcn_fdot2(w_u[a][m4 * 4],     h0,  acc[a][b], false);
                    acc[a][b] = __builtin_amdgcn_fdot2(w_u[a][m4 * 4 + 1], h1,  acc[a][b], false);
                    acc[a][b] = __builtin_amdgcn_fdot2(w_u[a][m4 * 4 + 2], h2v, acc[a][b], false);
                    acc[a][b] = __builtin_amdgcn_fdot2(w_u[a][m4 * 4 + 3], h3,  acc[a][b], false);
                }
            }
            if (c < 4) {
                const float* cb = sCo + b * 256 + ks * 32;
                #pragma unroll
                for (int m = 0; m < 8; m++) {
                    float4 cv = *(const float4*)(cb + m * 4);
                    a3[b] += w3[m].x * cv.x + w3[m].y * cv.y + w3[m].z * cv.z + w3[m].w * cv.w;
                }
            }
        }
        #pragma unroll
        for (int a = 0; a < 4; a++)
            #pragma unroll
            for (int b = 0; b < 8; b++) red[tid * 33 + a * 8 + b] = acc[a][b];
        #pragma unroll
        for (int b = 0; b < 8; b++) red2[tid * 9 + b] = a3[b];
        __syncthreads();

        // ---- elementwise (block-local) + publish raw h_o/c_o slice ----
        {
            float g4[4];
            #pragma unroll
            for (int a = 0; a < 4; a++) {
                float s = 0.f;
                #pragma unroll
                for (int k = 0; k < 8; k++)
                    s += red[(k * 32 + tl) * 33 + a * 8 + bb];
                s += ppL[bb * 128 + a * 32 + tl] + hyv[a];
                if (upok) s += bUv[a];
                if (lfok) s += bLv[a];
                g4[a] = s;
            }
            float ci = 0.f;
            #pragma unroll
            for (int k = 0; k < 8; k++) ci += red2[(k * 32 + tl) * 9 + bb];
            if (cok) ci += b_cc[(c & 3) * 32 + tl];
            const float cnew = sigm(g4[1]) * ci + sigm(g4[0]) * tanh_fast(g4[2]);
            const float hnew = sigm(g4[3]) * tanh_fast(cnew);
            const int base = ((i & 3) * 32 + j) * 2048 + bb * 256 + c * 32 + tl;
            st_f32(&Ho[base], hnew);
            st_f32(&Co[base], cnew);
        }
        drain_vmem();
        __syncthreads();
        if (tid == 0) st_flag(&HF[(i * 8 + c) * 16], BASE + (unsigned)(j + 1));
    }

    // ================= Final: condense ho(31,31) + MLP + softmax (bid 31) ==========
    if (bid == 31) {
        if (tid < 8) wait_ge(&HF[(31 * 8 + tid) * 16], 32u);
        __syncthreads();
        const float* HoF = Ho + (((31 & 3) * 32 + 31) * 2048);
        #pragma unroll
        for (int r = 0; r < 4; r++) {
            const int idx = r * 256 + tid;
            float2 v = ld_f32x2(HoF + idx * 2);
            sCo[idx * 2] = v.x; sCo[idx * 2 + 1] = v.y;
        }
        __syncthreads();
        // condense: hcond[b][o] = b_ch[o] + W_ch[o,:] @ ho[b,:]
        #pragma unroll 1
        for (int q = 0; q < 4; q++) {
            const int oo = tid + q * 256;
            const int b = oo >> 7, o = oo & 127;
            float a = b_ch[o];
            const float* wr = W_ch + (long)o * 256;
            const float* x = sCo + b * 256;
            for (int k = 0; k < 256; k += 4) {
                float4 wv = *(const float4*)(wr + k);
                float4 xv = *(const float4*)(x + k);
                a += wv.x * xv.x + wv.y * xv.y + wv.z * xv.z + wv.w * xv.w;
            }
            ppL[b * 128 + o] = a;
        }
        __syncthreads();
        float* m1 = red;          // [8][128]
        float* m2 = red + 1024;   // [8][128]
        for (int idx = tid; idx < 1024; idx += 256) {
            int b = idx >> 7, o = idx & 127;
            float a = b1[o];
            const float* wr = W1 + o * 128; const float* x = ppL + b * 128;
            for (int k = 0; k < 128; k++) a += wr[k] * x[k];
            m1[idx] = fmaxf(a, 0.f);
        }
        __syncthreads();
        for (int idx = tid; idx < 1024; idx += 256) {
            int b = idx >> 7, o = idx & 127;
            float a = b2[o];
            const float* wr = W2 + o * 128; const float* x = m1 + b * 128;
            for (int k = 0; k < 128; k++) a += wr[k] * x[k];
            m2[idx] = fmaxf(a, 0.f);
        }
        __syncthreads();
        if (tid < 8) {
            const int b = tid;
            float lg[3];
            for (int cc = 0; cc < 3; cc++) {
                float a = b3[cc];
                const float* wr = W3 + cc * 128; const float* x = m2 + b * 128;
                for (int k = 0; k < 128; k++) a += wr[k] * x[k];
                lg[cc] = a;
            }
            float m = fmaxf(lg[0], fmaxf(lg[1], lg[2]));
            float e0 = expf(lg[0] - m), e1 = expf(lg[1] - m), e2 = expf(lg[2] - m);
            float s = e0 + e1 + e2;
            out[b * 3 + 0] = e0 / s;
            out[b * 3 + 1] = e1 / s;
            out[b * 3 + 2] = e2 / s;
        }
    }
}

extern "C" void kernel_launch(void* const* d_in, const int* in_sizes, int n_in,
                              void* d_out, int out_size, void* d_ws, size_t ws_size,
                              hipStream_t stream) {
    const int*   premise    = (const int*)d_in[0];
    const int*   hypothesis = (const int*)d_in[1];
    const float* emb        = (const float*)d_in[2];
    const float* W_ih       = (const float*)d_in[3];
    const float* b_ih       = (const float*)d_in[4];
    const float* W_hh       = (const float*)d_in[5];
    const float* b_hh       = (const float*)d_in[6];
    const float* W_ch       = (const float*)d_in[7];
    const float* b_ch       = (const float*)d_in[8];
    const float* W_cc       = (const float*)d_in[9];
    const float* b_cc       = (const float*)d_in[10];
    const float* W1         = (const float*)d_in[11];
    const float* b1         = (const float*)d_in[12];
    const float* W2         = (const float*)d_in[13];
    const float* b2         = (const float*)d_in[14];
    const float* W3         = (const float*)d_in[15];
    const float* b3         = (const float*)d_in[16];
    float* out = (float*)d_out;
    float* ws  = (float*)d_ws;

    (void)in_sizes; (void)n_in; (void)out_size; (void)ws_size;

    grid_lstm_kernel<<<dim3(256), dim3(256), 0, stream>>>(
        premise, hypothesis, emb, W_ih, b_ih, W_hh, b_hh,
        W_ch, b_ch, W_cc, b_cc, W1, b1, W2, b2, W3, b3, out, ws);
}